// Round 5
// baseline (2293.914 us; speedup 1.0000x reference)
//
#include <hip/hip_runtime.h>
#include <hip/hip_fp16.h>
#include <cstdint>
#include <cstddef>

typedef __attribute__((ext_vector_type(8))) short short8;
typedef __attribute__((ext_vector_type(8))) _Float16 half8;
typedef __attribute__((ext_vector_type(4))) float f32x4;

// bf16 helpers (RNE)
__device__ __forceinline__ short f2bf(float x) {
  union { float f; unsigned u; } a; a.f = x;
  unsigned r = a.u + 0x7fff + ((a.u >> 16) & 1);
  return (short)(r >> 16);
}
__device__ __forceinline__ float bf2f(short s) {
  union { unsigned u; float f; } a;
  a.u = ((unsigned)(unsigned short)s) << 16; return a.f;
}

// async global->LDS, 16B/lane; dest = wave-uniform base + lane*16
__device__ __forceinline__ void ld16(const void* g, void* l) {
  __builtin_amdgcn_global_load_lds(
      (const __attribute__((address_space(1))) unsigned int*)g,
      (__attribute__((address_space(3))) unsigned int*)l, 16, 0, 0);
}

// top-3 insertion (strict >: earlier/lower-index wins ties)
__device__ __forceinline__ void ins3(float v, int j, float& v1, int& j1,
                                     float& v2, int& j2, float& v3, int& j3) {
  if (v > v3) {
    if (v > v1) { v3 = v2; j3 = j2; v2 = v1; j2 = j1; v1 = v; j1 = j; }
    else if (v > v2) { v3 = v2; j3 = j2; v2 = v; j2 = j; }
    else { v3 = v; j3 = j; }
  }
}

__global__ __launch_bounds__(256) void zfill(float4* __restrict__ p) {
  p[threadIdx.x] = make_float4(0.f, 0.f, 0.f, 0.f);
}

// ---------------------------------------------------------------------------
// conv1: x[16,3,256,256] -> h1[16,64,128,128] fp32, k=4 s=2 p=1, ReLU.
// (bit-identical to R1/R3 — encoder numerics must not change)
// ---------------------------------------------------------------------------
__global__ __launch_bounds__(256) void conv1_kernel(
    const float* __restrict__ x, const float* __restrict__ w,
    const float* __restrict__ bias, float* __restrict__ y)
{
  __shared__ __align__(16) float wl[64 * 48];
  __shared__ float bl[64];
  const int tid = threadIdx.x;
  for (int i = tid; i < 64 * 48; i += 256) wl[i] = w[i];
  if (tid < 64) bl[tid] = bias[tid];
  __syncthreads();
  const int n  = blockIdx.y;
  const int oh = blockIdx.x * 2 + (tid >> 7);
  const int ow = tid & 127;
  const float* xb = x + (size_t)n * 3 * 65536;
  const int ih0 = oh * 2 - 1, iw0 = ow * 2 - 1;
  float xin[48];
#pragma unroll
  for (int ic = 0; ic < 3; ++ic)
#pragma unroll
    for (int kh = 0; kh < 4; ++kh) {
      int ih = ih0 + kh;
      bool rok = (unsigned)ih < 256u;
#pragma unroll
      for (int kw = 0; kw < 4; ++kw) {
        int iw = iw0 + kw;
        xin[ic * 16 + kh * 4 + kw] =
            (rok && (unsigned)iw < 256u) ? xb[ic * 65536 + ih * 256 + iw] : 0.f;
      }
    }
  float* yb = y + (size_t)n * 64 * 16384 + oh * 128 + ow;
  for (int oc = 0; oc < 64; ++oc) {
    float acc = bl[oc];
    const float* wo = &wl[oc * 48];
#pragma unroll
    for (int j = 0; j < 48; ++j) acc = fmaf(wo[j], xin[j], acc);
    yb[(size_t)oc * 16384] = fmaxf(acc, 0.f);
  }
}

// ---------------------------------------------------------------------------
// conv_s2: k=4 s=2 p=1 implicit GEMM, fp32 (bit-identical accumulation to R3;
// B-reads use literal offsets 0/76/152/228 so the compiler can emit
// ds_read2_b32 / offset-immediates — same values, fewer LDS+VALU ops).
// ---------------------------------------------------------------------------
template <int CIN, int HIN, int COUT, bool RELU>
__global__ __launch_bounds__(256) void conv_s2(
    const float* __restrict__ x, const float* __restrict__ w,
    const float* __restrict__ bias, float* __restrict__ y)
{
  constexpr int HOUT = HIN / 2;
  constexpr int TILES = HOUT / 8;
  __shared__ __align__(16) float Wl[64 * 68];
  __shared__ __align__(16) float Xl[4 * 342];
  __shared__ float bl[64];
  const int tid = threadIdx.x;
  const int tx = tid & 15, ty = tid >> 4;
  const int oh0 = (blockIdx.x / TILES) * 8, ow0 = (blockIdx.x % TILES) * 8;
  const int oc0 = blockIdx.y * 64;
  const int n = blockIdx.z;
  if (tid < 64) bl[tid] = bias[oc0 + tid];
  const float* xn = x + (size_t)n * CIN * (HIN * HIN);
  float acc[4][4] = {};
  // xoff[q] = xoff0 + 76*q  (p = tx + 16q; exact identity)
  const int xoff0 = 2 * (tx >> 3) * 19 + 2 * (tx & 7);
  const int ihb = 2 * oh0 - 1, iwb = 2 * ow0 - 1;
  for (int ic0 = 0; ic0 < CIN; ic0 += 4) {
    __syncthreads();
#pragma unroll
    for (int it = 0; it < 4; ++it) {
      int i = tid + it * 256;
      int oc_l = i >> 4, kq = i & 15;
      const float* wp = &w[((size_t)(oc0 + oc_l) * CIN + ic0) * 16 + kq * 4];
      float4 wv = *(const float4*)wp;
      Wl[(kq * 4 + 0) * 68 + oc_l] = wv.x;
      Wl[(kq * 4 + 1) * 68 + oc_l] = wv.y;
      Wl[(kq * 4 + 2) * 68 + oc_l] = wv.z;
      Wl[(kq * 4 + 3) * 68 + oc_l] = wv.w;
    }
    for (int i = tid; i < 4 * 342; i += 256) {
      int ic_l = i / 342, rem = i - ic_l * 342;
      int rr = rem / 19, cc = rem - rr * 19;
      int ih = ihb + rr, iw = iwb + cc;
      float v = 0.f;
      if ((unsigned)ih < (unsigned)HIN && (unsigned)iw < (unsigned)HIN)
        v = xn[(size_t)(ic0 + ic_l) * (HIN * HIN) + ih * HIN + iw];
      Xl[i] = v;
    }
    __syncthreads();
#pragma unroll
    for (int ic_l = 0; ic_l < 4; ++ic_l) {
#pragma unroll
      for (int tap = 0; tap < 16; ++tap) {
        const int k = ic_l * 16 + tap;
        const int kh = tap >> 2, kw = tap & 3;
        float4 a = *(const float4*)&Wl[k * 68 + ty * 4];
        const float* bp = &Xl[ic_l * 342 + kh * 19 + kw + xoff0];
        float av[4] = {a.x, a.y, a.z, a.w};
        float bb[4] = {bp[0], bp[76], bp[152], bp[228]};
#pragma unroll
        for (int i2 = 0; i2 < 4; ++i2)
#pragma unroll
          for (int q = 0; q < 4; ++q)
            acc[i2][q] = fmaf(av[i2], bb[q], acc[i2][q]);
      }
    }
  }
  float* yn = y + ((size_t)n * COUT + oc0) * (HOUT * HOUT);
#pragma unroll
  for (int i = 0; i < 4; ++i) {
    float bbias = bl[ty * 4 + i];
#pragma unroll
    for (int q = 0; q < 4; ++q) {
      int p = tx + 16 * q;
      int u = p >> 3, v = p & 7;
      float vv = acc[i][q] + bbias;
      if (RELU) vv = fmaxf(vv, 0.f);
      yn[(size_t)(ty * 4 + i) * (HOUT * HOUT) + (oh0 + u) * HOUT + (ow0 + v)] = vv;
    }
  }
}

// ---------------------------------------------------------------------------
// cb_convert: cb fp32 -> bf16 hi/lo (decoder) + fp16 (vq approx).
// ---------------------------------------------------------------------------
__global__ __launch_bounds__(256) void cb_convert(
    const float* __restrict__ cb, short* __restrict__ cbh,
    short* __restrict__ cbl, unsigned short* __restrict__ cbf)
{
  const int g = blockIdx.x * 256 + threadIdx.x;
  const float* p = cb + (size_t)g * 8;
  short hs[8], ls[8];
  unsigned short fs[8];
#pragma unroll
  for (int u = 0; u < 8; ++u) {
    float v = p[u];
    short h = f2bf(v);
    hs[u] = h;
    ls[u] = f2bf(v - bf2f(h));
    fs[u] = __half_as_ushort(__float2half_rn(v));
  }
  *(short8*)(cbh + (size_t)g * 8) = *(short8*)hs;
  *(short8*)(cbl + (size_t)g * 8) = *(short8*)ls;
  *(short8*)(cbf + (size_t)g * 8) = *(short8*)fs;
}

// ---------------------------------------------------------------------------
// featT_prep2: feat[16][256][1024] fp32 -> featT fp32 [tok][256] (exact bits,
// just transposed) + ftf16 fp16 [tok][256] for the MFMA approx.
// ---------------------------------------------------------------------------
__global__ __launch_bounds__(256) void featT_prep2(
    const float* __restrict__ feat, float* __restrict__ featT,
    unsigned short* __restrict__ ftf)
{
  __shared__ float T[64][65];
  const int b = blockIdx.z, k0 = blockIdx.y * 64, t0 = blockIdx.x * 64;
  const float* fb = feat + ((size_t)b * 256 + k0) * 1024 + t0;
  const int tid = threadIdx.x;
#pragma unroll
  for (int r = 0; r < 16; ++r) {
    int idx = r * 256 + tid;
    int kk = idx >> 6, tt = idx & 63;
    T[tt][kk] = fb[(size_t)kk * 1024 + tt];
  }
  __syncthreads();
#pragma unroll
  for (int r = 0; r < 4; ++r) {
    int i = r * 256 + tid;            // 0..1023
    int tt = i >> 4, kq = i & 15;
    float v0 = T[tt][kq * 4 + 0], v1 = T[tt][kq * 4 + 1];
    float v2 = T[tt][kq * 4 + 2], v3 = T[tt][kq * 4 + 3];
    size_t off = ((size_t)(b * 1024 + t0 + tt)) * 256 + k0 + kq * 4;
    *(float4*)(featT + off) = make_float4(v0, v1, v2, v3);
    ushort4 fv;
    fv.x = __half_as_ushort(__float2half_rn(v0));
    fv.y = __half_as_ushort(__float2half_rn(v1));
    fv.z = __half_as_ushort(__float2half_rn(v2));
    fv.w = __half_as_ushort(__float2half_rn(v3));
    *(ushort4*)(ftf + off) = fv;
  }
}

// ---------------------------------------------------------------------------
// vq_mfma: approx scores via ONE fp16 MFMA; per-block TOP-3 per token.
// Block 128 codes x 128 tokens; exact top-6 rescore follows.
// ---------------------------------------------------------------------------
__global__ __launch_bounds__(256) void vq_mfma(
    const unsigned short* __restrict__ cbf, const unsigned short* __restrict__ ftf,
    float* __restrict__ pval3, int* __restrict__ pidx3)
{
  __shared__ __align__(16) unsigned short Af[4096];
  __shared__ __align__(16) unsigned short Bf[4096];
  const int tid = threadIdx.x;
  const int w = tid >> 6, lane = tid & 63;
  const int wm = w >> 1, wn = w & 1;
  const int code0 = blockIdx.y * 128, tok0 = blockIdx.x * 128;
  const int kgl = lane >> 4, cl = lane & 15;

  f32x4 acc[4][4];
#pragma unroll
  for (int i = 0; i < 4; ++i)
#pragma unroll
    for (int j = 0; j < 4; ++j) acc[i][j] = (f32x4){0.f, 0.f, 0.f, 0.f};

  for (int kc = 0; kc < 256; kc += 32) {
    __syncthreads();
#pragma unroll
    for (int rep = 0; rep < 2; ++rep) {
      int e = rep * 256 + tid;
      int kg = e >> 7, m = e & 127;
      size_t goA = (size_t)(code0 + m) * 256 + kc + kg * 8;
      size_t goB = (size_t)(tok0 + m) * 256 + kc + kg * 8;
      int lo = (e & ~63) * 8;
      ld16(cbf + goA, Af + lo);
      ld16(ftf + goB, Bf + lo);
    }
    __syncthreads();
    half8 a4[4], b4[4];
#pragma unroll
    for (int mt = 0; mt < 4; ++mt)
      a4[mt] = *(const half8*)&Af[(kgl * 128 + wm * 64 + mt * 16 + cl) * 8];
#pragma unroll
    for (int nt = 0; nt < 4; ++nt)
      b4[nt] = *(const half8*)&Bf[(kgl * 128 + wn * 64 + nt * 16 + cl) * 8];
#pragma unroll
    for (int mt = 0; mt < 4; ++mt)
#pragma unroll
      for (int nt = 0; nt < 4; ++nt)
        acc[mt][nt] = __builtin_amdgcn_mfma_f32_16x16x32_f16(a4[mt], b4[nt], acc[mt][nt], 0, 0, 0);
  }
  __syncthreads();

  float* Sv = (float*)Af;   // [2 wm][128 tok][3]
  int* Si = (int*)Bf;
#pragma unroll
  for (int nt = 0; nt < 4; ++nt) {
    float v1 = -3.4e38f, v2 = -3.4e38f, v3 = -3.4e38f;
    int j1 = 0, j2 = 0, j3 = 0;
#pragma unroll
    for (int mt = 0; mt < 4; ++mt) {
      int cb2 = code0 + wm * 64 + mt * 16 + kgl * 4;
      f32x4 a = acc[mt][nt];
#pragma unroll
      for (int r = 0; r < 4; ++r) ins3(a[r], cb2 + r, v1, j1, v2, j2, v3, j3);
    }
    for (int mk = 16; mk < 64; mk <<= 1) {
      float ov1 = __shfl_xor(v1, mk), ov2 = __shfl_xor(v2, mk), ov3 = __shfl_xor(v3, mk);
      int oj1 = __shfl_xor(j1, mk), oj2 = __shfl_xor(j2, mk), oj3 = __shfl_xor(j3, mk);
      ins3(ov1, oj1, v1, j1, v2, j2, v3, j3);
      ins3(ov2, oj2, v1, j1, v2, j2, v3, j3);
      ins3(ov3, oj3, v1, j1, v2, j2, v3, j3);
    }
    if (lane < 16) {
      int tl = wn * 64 + nt * 16 + lane;
      Sv[(wm * 128 + tl) * 3 + 0] = v1;
      Sv[(wm * 128 + tl) * 3 + 1] = v2;
      Sv[(wm * 128 + tl) * 3 + 2] = v3;
      Si[(wm * 128 + tl) * 3 + 0] = j1;
      Si[(wm * 128 + tl) * 3 + 1] = j2;
      Si[(wm * 128 + tl) * 3 + 2] = j3;
    }
  }
  __syncthreads();
  if (tid < 128) {
    int tl = tid;
    float v1 = Sv[tl * 3], v2 = Sv[tl * 3 + 1], v3 = Sv[tl * 3 + 2];
    int j1 = Si[tl * 3], j2 = Si[tl * 3 + 1], j3 = Si[tl * 3 + 2];
    ins3(Sv[(128 + tl) * 3 + 0], Si[(128 + tl) * 3 + 0], v1, j1, v2, j2, v3, j3);
    ins3(Sv[(128 + tl) * 3 + 1], Si[(128 + tl) * 3 + 1], v1, j1, v2, j2, v3, j3);
    ins3(Sv[(128 + tl) * 3 + 2], Si[(128 + tl) * 3 + 2], v1, j1, v2, j2, v3, j3);
    size_t base = (size_t)blockIdx.y * 3 * 16384 + tok0 + tl;
    pval3[base] = v1;  pval3[base + 16384] = v2;  pval3[base + 32768] = v3;
    pidx3[base] = j1;  pidx3[base + 16384] = j2;  pidx3[base + 32768] = j3;
  }
}

// ---------------------------------------------------------------------------
// vq_rescore: merge 64x3 partials -> top-6 candidates -> exact fp32 dots
// vs featT[tok][256] (bit-identical values/order to R3) -> final index.
// ---------------------------------------------------------------------------
__global__ __launch_bounds__(256) void vq_rescore(
    const float* __restrict__ pval3, const int* __restrict__ pidx3,
    const float* __restrict__ featT, const float* __restrict__ cb,
    int* __restrict__ fidx, float* __restrict__ idx_out)
{
  const int t = blockIdx.x * 256 + threadIdx.x;
  float vs[6] = {-3.4e38f, -3.4e38f, -3.4e38f, -3.4e38f, -3.4e38f, -3.4e38f};
  int is[6] = {0, 0, 0, 0, 0, 0};
  for (int gi = 0; gi < 192; ++gi) {
    float v = pval3[((size_t)gi << 14) + t];
    int j = pidx3[((size_t)gi << 14) + t];
    if (v > vs[5]) {
      vs[5] = v; is[5] = j;
#pragma unroll
      for (int k = 5; k > 0; --k)
        if (vs[k] > vs[k - 1]) {
          float tv = vs[k]; vs[k] = vs[k - 1]; vs[k - 1] = tv;
          int ti = is[k]; is[k] = is[k - 1]; is[k - 1] = ti;
        }
    }
  }
  const float4* fc = (const float4*)(featT + (size_t)t * 256);
  const float4* cp[6];
  float sc[6] = {0.f, 0.f, 0.f, 0.f, 0.f, 0.f};
#pragma unroll
  for (int c = 0; c < 6; ++c) cp[c] = (const float4*)(cb + (size_t)is[c] * 256);
  for (int k4 = 0; k4 < 64; ++k4) {
    float4 f = fc[k4];
#pragma unroll
    for (int c = 0; c < 6; ++c) {
      float4 wv = cp[c][k4];
      sc[c] = fmaf(wv.x, f.x, fmaf(wv.y, f.y, fmaf(wv.z, f.z, fmaf(wv.w, f.w, sc[c]))));
    }
  }
  float best = sc[0]; int bi = is[0];
#pragma unroll
  for (int c = 1; c < 6; ++c)
    if (sc[c] > best || (sc[c] == best && is[c] < bi)) { best = sc[c]; bi = is[c]; }
  fidx[t] = bi;
  idx_out[t] = (float)bi;
}

// ---------------------------------------------------------------------------
// wpack / gather2 / deconv_mfma / deconv3  (decoder — unchanged from R3)
// ---------------------------------------------------------------------------
template <int COUT, int CIN>
__global__ __launch_bounds__(256) void wpack(
    const float* __restrict__ w, short* __restrict__ Ah, short* __restrict__ Al)
{
  constexpr int K = 4 * CIN;
  const int idx = blockIdx.x * 256 + threadIdx.x;
  const int par = idx / (COUT * K);
  const int rem = idx % (COUT * K);
  const int oc = rem / K;
  const int k = rem % K;
  const int kk = k / CIN, ic = k % CIN;
  const int kh = 2 * (kk >> 1) + (par >> 1);
  const int kw = 2 * (kk & 1) + (par & 1);
  float v = w[(((size_t)oc * CIN + ic) * 4 + kh) * 4 + kw];
  short h = f2bf(v);
  Ah[idx] = h;
  Al[idx] = f2bf(v - bf2f(h));
}

__global__ __launch_bounds__(256) void gather2(
    const short* __restrict__ cbh, const short* __restrict__ cbl,
    const int* __restrict__ fidx, short* __restrict__ qTh, short* __restrict__ qTl)
{
  const int tid = threadIdx.x;
  const int gt = blockIdx.x * 64 + (tid >> 2);
  const int part = tid & 3;
  const int code = fidx[gt];
  const short8* sh = (const short8*)(cbh + (size_t)code * 256 + part * 64);
  const short8* sl = (const short8*)(cbl + (size_t)code * 256 + part * 64);
  short8* dh = (short8*)(qTh + (size_t)gt * 256 + part * 64);
  short8* dl = (short8*)(qTl + (size_t)gt * 256 + part * 64);
#pragma unroll
  for (int j = 0; j < 8; ++j) { dh[j] = sh[j]; dl[j] = sl[j]; }
}

template <int CIN, int GRID, int COUT, int NPX, int WM, int WN, bool OUT_HALF>
__global__ __launch_bounds__(256) void deconv_mfma(
    const short* __restrict__ inh, const short* __restrict__ inl,
    const short* __restrict__ Aph, const short* __restrict__ Apl,
    const float* __restrict__ bias, void* __restrict__ out_h,
    void* __restrict__ out_l, const short* __restrict__ zp)
{
  constexpr int K = 4 * CIN, HOUT = 2 * GRID, AE = 4 * COUT, BE = 4 * NPX;
  constexpr int GS = (GRID == 32) ? 5 : 6;
  __shared__ __align__(16) short AhL[AE * 8];
  __shared__ __align__(16) short AlL[AE * 8];
  __shared__ __align__(16) short BhL[BE * 8];
  __shared__ __align__(16) short BlL[BE * 8];
  __shared__ float bl[COUT];
  const int tid = threadIdx.x;
  const int w = tid >> 6, lane = tid & 63;
  const int wm = w / WN, wn = w % WN;
  const int kgl = lane >> 4, cl = lane & 15;
  const int par = blockIdx.y, n = blockIdx.z;
  const int pr = par >> 1, pc = par & 1;
  const int Ut0 = blockIdx.x * (NPX / GRID);
  if (tid < COUT) bl[tid] = bias[tid];

  f32x4 acc[4][4];
#pragma unroll
  for (int i = 0; i < 4; ++i)
#pragma unroll
    for (int j = 0; j < 4; ++j) acc[i][j] = (f32x4){0.f, 0.f, 0.f, 0.f};

  for (int kc = 0; kc < K; kc += 32) {
    const int kk = kc / CIN, ic0 = kc % CIN;
    const int dr = (kk >> 1) + pr - 1, dc = (kk & 1) + pc - 1;
    __syncthreads();
#pragma unroll
    for (int rep = 0; rep < AE / 256; ++rep) {
      int e = rep * 256 + tid;
      int kg = e / COUT, oc_l = e % COUT;
      size_t go = ((size_t)(par * COUT + oc_l)) * K + kc + kg * 8;
      int lo = (e & ~63) * 8;
      ld16(Aph + go, AhL + lo);
      ld16(Apl + go, AlL + lo);
    }
#pragma unroll
    for (int rep = 0; rep < BE / 256; ++rep) {
      int e = rep * 256 + tid;
      int kg = e / NPX, m = e % NPX;
      int sU = Ut0 + (m >> GS) + dr;
      int sV = (m & (GRID - 1)) + dc;
      bool ok = (unsigned)sU < (unsigned)GRID && (unsigned)sV < (unsigned)GRID;
      long pix = (long)(n * GRID + sU) * GRID + sV;
      size_t go = (size_t)(pix * CIN + ic0 + kg * 8);
      int lo = (e & ~63) * 8;
      ld16(ok ? inh + go : zp, BhL + lo);
      ld16(ok ? inl + go : zp, BlL + lo);
    }
    __syncthreads();
    short8 ah[4], al[4], bh[4], blo[4];
#pragma unroll
    for (int mt = 0; mt < 4; ++mt) {
      int row = kgl * COUT + wm * 64 + mt * 16 + cl;
      ah[mt] = *(const short8*)&AhL[row * 8];
      al[mt] = *(const short8*)&AlL[row * 8];
    }
#pragma unroll
    for (int nt = 0; nt < 4; ++nt) {
      int row = kgl * NPX + wn * 64 + nt * 16 + cl;
      bh[nt] = *(const short8*)&BhL[row * 8];
      blo[nt] = *(const short8*)&BlL[row * 8];
    }
#pragma unroll
    for (int mt = 0; mt < 4; ++mt)
#pragma unroll
      for (int nt = 0; nt < 4; ++nt) {
        acc[mt][nt] = __builtin_amdgcn_mfma_f32_16x16x32_bf16(
            ah[mt], bh[nt], acc[mt][nt], 0, 0, 0);
        acc[mt][nt] = __builtin_amdgcn_mfma_f32_16x16x32_bf16(
            ah[mt], blo[nt], acc[mt][nt], 0, 0, 0);
        acc[mt][nt] = __builtin_amdgcn_mfma_f32_16x16x32_bf16(
            al[mt], bh[nt], acc[mt][nt], 0, 0, 0);
      }
  }
#pragma unroll
  for (int mt = 0; mt < 4; ++mt) {
    const int oc = wm * 64 + mt * 16 + kgl * 4;
    const float4 bv = *(const float4*)&bl[oc];
#pragma unroll
    for (int nt = 0; nt < 4; ++nt) {
      const int px = wn * 64 + nt * 16 + cl;
      const int U = Ut0 + (px >> GS), V = px & (GRID - 1);
      const int r = 2 * U + pr, c = 2 * V + pc;
      const size_t ob = ((size_t)n * HOUT * HOUT + (size_t)r * HOUT + c) * COUT + oc;
      float v0 = fmaxf(acc[mt][nt][0] + bv.x, 0.f);
      float v1 = fmaxf(acc[mt][nt][1] + bv.y, 0.f);
      float v2 = fmaxf(acc[mt][nt][2] + bv.z, 0.f);
      float v3 = fmaxf(acc[mt][nt][3] + bv.w, 0.f);
      if constexpr (OUT_HALF) {
        ushort4 s;
        s.x = __half_as_ushort(__float2half(v0));
        s.y = __half_as_ushort(__float2half(v1));
        s.z = __half_as_ushort(__float2half(v2));
        s.w = __half_as_ushort(__float2half(v3));
        *(ushort4*)((unsigned short*)out_h + ob) = s;
      } else {
        short4 hh, ll;
        hh.x = f2bf(v0); ll.x = f2bf(v0 - bf2f(hh.x));
        hh.y = f2bf(v1); ll.y = f2bf(v1 - bf2f(hh.y));
        hh.z = f2bf(v2); ll.z = f2bf(v2 - bf2f(hh.z));
        hh.w = f2bf(v3); ll.w = f2bf(v3 - bf2f(hh.w));
        *(short4*)((short*)out_h + ob) = hh;
        *(short4*)((short*)out_l + ob) = ll;
      }
    }
  }
}

__global__ __launch_bounds__(256) void deconv3_kernel(
    const __half* __restrict__ d2, const float* __restrict__ w,
    const float* __restrict__ bias, float* __restrict__ y)
{
  __shared__ __align__(16) float Xl[108 * 68];
  __shared__ __align__(16) float wl[4 * 4 * 3 * 64];
  const int tid = threadIdx.x;
  for (int i = tid; i < 3072; i += 256) {
    int oc = i >> 10, ic = (i >> 4) & 63, kh = (i >> 2) & 3, kw = i & 3;
    int par = (kh & 1) * 2 + (kw & 1), kidx = (kh >> 1) * 2 + (kw >> 1);
    wl[((par * 4 + kidx) * 3 + oc) * 64 + ic] = w[i];
  }
  const int n = blockIdx.z, r0 = blockIdx.y * 8, c0 = blockIdx.x * 32;
  const int gr0 = (r0 >> 1) - 1, gc0 = (c0 >> 1) - 1;
  for (int e = tid; e < 1728; e += 256) {
    int pl = e >> 4, sub = e & 15;
    int rr = pl / 18, cc = pl - rr * 18;
    int gr = gr0 + rr, gc = gc0 + cc;
    float4 v = make_float4(0.f, 0.f, 0.f, 0.f);
    if ((unsigned)gr < 128u && (unsigned)gc < 128u) {
      const __half2* p =
          (const __half2*)(d2 + ((size_t)(n * 16384 + gr * 128 + gc) * 64 + sub * 4));
      float2 f0 = __half22float2(p[0]);
      float2 f1 = __half22float2(p[1]);
      v = make_float4(f0.x, f0.y, f1.x, f1.y);
    }
    *(float4*)&Xl[pl * 68 + sub * 4] = v;
  }
  __syncthreads();
  const int wv = tid >> 6, lane = tid & 63;
  const int pr = wv >> 1, pc = wv & 1;
  const int Ul = lane >> 4, Vl = lane & 15;
  float a0 = bias[0], a1 = bias[1], a2 = bias[2];
  const int parb = wv * 768;
#pragma unroll
  for (int ic4 = 0; ic4 < 16; ++ic4) {
    float4 xv[4];
#pragma unroll
    for (int t = 0; t < 4; ++t) {
      int lr = Ul + (t >> 1) + pr, lc = Vl + (t & 1) + pc;
      xv[t] = *(const float4*)&Xl[(lr * 18 + lc) * 68 + ic4 * 4];
    }
#pragma unroll
    for (int t = 0; t < 4; ++t) {
      float4 w0 = *(const float4*)&wl[parb + (t * 3 + 0) * 64 + ic4 * 4];
      float4 w1 = *(const float4*)&wl[parb + (t * 3 + 1) * 64 + ic4 * 4];
      float4 w2 = *(const float4*)&wl[parb + (t * 3 + 2) * 64 + ic4 * 4];
      a0 = fmaf(w0.x, xv[t].x, fmaf(w0.y, xv[t].y, fmaf(w0.z, xv[t].z, fmaf(w0.w, xv[t].w, a0))));
      a1 = fmaf(w1.x, xv[t].x, fmaf(w1.y, xv[t].y, fmaf(w1.z, xv[t].z, fmaf(w1.w, xv[t].w, a1))));
      a2 = fmaf(w2.x, xv[t].x, fmaf(w2.y, xv[t].y, fmaf(w2.z, xv[t].z, fmaf(w2.w, xv[t].w, a2))));
    }
  }
  const int r = r0 + 2 * Ul + pr, c = c0 + 2 * Vl + pc;
  float* yn = y + (size_t)n * 3 * 65536 + r * 256 + c;
  yn[0] = a0;
  yn[65536] = a1;
  yn[131072] = a2;
}

// ---------------------------------------------------------------------------
extern "C" void kernel_launch(void* const* d_in, const int* in_sizes, int n_in,
                              void* d_out, int out_size, void* d_ws, size_t ws_size,
                              hipStream_t stream)
{
  const float* x   = (const float*)d_in[0];
  const float* ew1 = (const float*)d_in[1];
  const float* eb1 = (const float*)d_in[2];
  const float* ew2 = (const float*)d_in[3];
  const float* eb2 = (const float*)d_in[4];
  const float* ew3 = (const float*)d_in[5];
  const float* eb3 = (const float*)d_in[6];
  const float* cb  = (const float*)d_in[7];
  const float* dw1 = (const float*)d_in[8];
  const float* db1 = (const float*)d_in[9];
  const float* dw2 = (const float*)d_in[10];
  const float* db2 = (const float*)d_in[11];
  const float* dw3 = (const float*)d_in[12];
  const float* db3 = (const float*)d_in[13];

  float* recon = (float*)d_out;
  float* idxf  = (float*)d_out + 3145728;
  unsigned short* zp = (unsigned short*)d_out;   // [0,4K) zero page (re-zeroed)

  char* ws = (char*)d_ws;
  // Workspace map (max 96 MiB, liveness-aliased):
  float* h1   = (float*)ws;                         // [0,64M)  conv1 out fp32
  float* h2   = (float*)(ws + 67108864);            // [64M,96M) conv2 out fp32
  float* feat = (float*)ws;                         // [0,16M)  conv3 out (h1 dead)
  short* cbh  = (short*)(ws + 16777216);            // [16M,20M)
  short* cbl  = (short*)(ws + 20971520);            // [20M,24M)
  unsigned short* cbf16 = (unsigned short*)(ws + 25165824);  // [24M,28M)
  float* featT = (float*)(ws + 29360128);           // [28M,44M) fp32 [tok][256]
  unsigned short* ftf16 = (unsigned short*)(ws + 46137344);  // [44M,52M)
  float* pval3 = (float*)(ws + 54525952);           // [52M,64M)
  int*   pidx3 = (int*)(ws + 67108864);             // [64M,76M) (h2 dead)
  int*   fidx  = (int*)(ws + 94371840);             // [90M,+64K)
  short* A1h = (short*)(ws + 54525952);             // [52M..) after rescore
  short* A1l = (short*)(ws + 55574528);
  short* A2h = (short*)(ws + 56623104);
  short* A2l = (short*)(ws + 56885248);
  short* qTh = (short*)ws;                          // [0,8M)  (feat dead)
  short* qTl = (short*)(ws + 8388608);              // [8M,16M)
  short* d1h = (short*)(ws + 67108864);             // [64M,80M) (pidx3 dead)
  short* d1l = (short*)(ws + 83886080);             // [80M,96M) (fidx dead post-gather2)
  __half* d2 = (__half*)ws;                         // [0,32M)  (qT/cb* dead)

  zfill<<<dim3(1), 256, 0, stream>>>((float4*)zp);

  conv1_kernel<<<dim3(64, 16), 256, 0, stream>>>(x, ew1, eb1, h1);
  conv_s2<64, 128, 128, true><<<dim3(64, 2, 16), 256, 0, stream>>>(h1, ew2, eb2, h2);
  conv_s2<128, 64, 256, false><<<dim3(16, 4, 16), 256, 0, stream>>>(h2, ew3, eb3, feat);

  cb_convert<<<dim3(1024), 256, 0, stream>>>(cb, cbh, cbl, cbf16);
  featT_prep2<<<dim3(16, 4, 16), 256, 0, stream>>>(feat, featT, ftf16);
  vq_mfma<<<dim3(128, 64), 256, 0, stream>>>(cbf16, ftf16, pval3, pidx3);
  vq_rescore<<<dim3(64), 256, 0, stream>>>(pval3, pidx3, featT, cb, fidx, idxf);

  wpack<128, 256><<<dim3(2048), 256, 0, stream>>>(dw1, A1h, A1l);
  wpack<64, 128><<<dim3(512), 256, 0, stream>>>(dw2, A2h, A2l);
  gather2<<<dim3(256), 256, 0, stream>>>(cbh, cbl, fidx, qTh, qTl);

  deconv_mfma<256, 32, 128, 128, 2, 2, false>
      <<<dim3(8, 4, 16), 256, 0, stream>>>(qTh, qTl, A1h, A1l, db1, d1h, d1l, (const short*)zp);
  deconv_mfma<128, 64, 64, 256, 1, 4, true>
      <<<dim3(16, 4, 16), 256, 0, stream>>>(d1h, d1l, A2h, A2l, db2, d2, d2, (const short*)zp);
  deconv3_kernel<<<dim3(8, 32, 16), 256, 0, stream>>>(d2, dw3, db3, recon);
}

// Round 7
// 1720.197 us; speedup vs baseline: 1.3335x; 1.3335x over previous
//
#include <hip/hip_runtime.h>
#include <hip/hip_fp16.h>
#include <cstdint>
#include <cstddef>

typedef __attribute__((ext_vector_type(8))) short short8;
typedef __attribute__((ext_vector_type(4))) float f32x4;

// bf16 helpers (RNE)
__device__ __forceinline__ short f2bf(float x) {
  union { float f; unsigned u; } a; a.f = x;
  unsigned r = a.u + 0x7fff + ((a.u >> 16) & 1);
  return (short)(r >> 16);
}
__device__ __forceinline__ float bf2f(short s) {
  union { unsigned u; float f; } a;
  a.u = ((unsigned)(unsigned short)s) << 16; return a.f;
}

// async global->LDS, 16B/lane; dest = wave-uniform base + lane*16
__device__ __forceinline__ void ld16(const void* g, void* l) {
  __builtin_amdgcn_global_load_lds(
      (const __attribute__((address_space(1))) unsigned int*)g,
      (__attribute__((address_space(3))) unsigned int*)l, 16, 0, 0);
}

__global__ __launch_bounds__(256) void zfill(float4* __restrict__ p) {
  p[threadIdx.x] = make_float4(0.f, 0.f, 0.f, 0.f);
}

// ---------------------------------------------------------------------------
// conv1: x[16,3,256,256] -> h1[16,64,128,128] fp32, k=4 s=2 p=1, ReLU.
// (verbatim R3 — encoder numerics must stay bit-exact)
// ---------------------------------------------------------------------------
__global__ __launch_bounds__(256) void conv1_kernel(
    const float* __restrict__ x, const float* __restrict__ w,
    const float* __restrict__ bias, float* __restrict__ y)
{
  __shared__ __align__(16) float wl[64 * 48];
  __shared__ float bl[64];
  const int tid = threadIdx.x;
  for (int i = tid; i < 64 * 48; i += 256) wl[i] = w[i];
  if (tid < 64) bl[tid] = bias[tid];
  __syncthreads();
  const int n  = blockIdx.y;
  const int oh = blockIdx.x * 2 + (tid >> 7);
  const int ow = tid & 127;
  const float* xb = x + (size_t)n * 3 * 65536;
  const int ih0 = oh * 2 - 1, iw0 = ow * 2 - 1;
  float xin[48];
#pragma unroll
  for (int ic = 0; ic < 3; ++ic)
#pragma unroll
    for (int kh = 0; kh < 4; ++kh) {
      int ih = ih0 + kh;
      bool rok = (unsigned)ih < 256u;
#pragma unroll
      for (int kw = 0; kw < 4; ++kw) {
        int iw = iw0 + kw;
        xin[ic * 16 + kh * 4 + kw] =
            (rok && (unsigned)iw < 256u) ? xb[ic * 65536 + ih * 256 + iw] : 0.f;
      }
    }
  float* yb = y + (size_t)n * 64 * 16384 + oh * 128 + ow;
  for (int oc = 0; oc < 64; ++oc) {
    float acc = bl[oc];
    const float* wo = &wl[oc * 48];
#pragma unroll
    for (int j = 0; j < 48; ++j) acc = fmaf(wo[j], xin[j], acc);
    yb[(size_t)oc * 16384] = fmaxf(acc, 0.f);
  }
}

// ---------------------------------------------------------------------------
// conv_s2: k=4 s=2 p=1 implicit GEMM fp32, BIT-IDENTICAL accumulation to R3
// (same per-element chain: ic0 asc, ic_l asc, tap asc, same fmaf nesting).
// Restructured: block 64oc x 128px (16x8 tile), thread 8oc x 4px.
// Per tap: 2x ds_read_b128 (A) + 4x ds_read_b32 (B) : 32 FMA -> VALU-bound.
// Xl row stride 20 (banks: 40*(tx>>3)+2*(tx&7) -> <=2-way, free).
// ---------------------------------------------------------------------------
template <int CIN, int HIN, int COUT, bool RELU>
__global__ __launch_bounds__(256) void conv_s2(
    const float* __restrict__ x, const float* __restrict__ w,
    const float* __restrict__ bias, float* __restrict__ y)
{
  constexpr int HOUT = HIN / 2;
  constexpr int TW = HOUT / 8;          // col tiles (8 cols each)
  __shared__ __align__(16) float Wl[64 * 68];
  __shared__ __align__(16) float Xl[4 * 680];   // [ic][34 rows][20 cols]
  __shared__ float bl[64];
  const int tid = threadIdx.x;
  const int ty = tid >> 5, tx = tid & 31;       // 8 oc-groups x 32 px-groups
  const int th = blockIdx.x / TW, tw = blockIdx.x % TW;
  const int oh0 = th * 16, ow0 = tw * 8;
  const int oc0 = blockIdx.y * 64;
  const int n = blockIdx.z;
  if (tid < 64) bl[tid] = bias[oc0 + tid];
  const float* xn = x + (size_t)n * CIN * (HIN * HIN);
  float acc[8][4] = {};
  const int brow0 = 2 * (tx >> 3);              // + kh + 8q at use
  const int bcol0 = 2 * (tx & 7);               // + kw at use
  const int ihb = 2 * oh0 - 1, iwb = 2 * ow0 - 1;
  for (int ic0 = 0; ic0 < CIN; ic0 += 4) {
    __syncthreads();
    // stage weights: 64 oc x 64 k (k = ic_l*16 + tap), transposed (R3 pattern)
#pragma unroll
    for (int it = 0; it < 4; ++it) {
      int i = tid + it * 256;
      int oc_l = i >> 4, kq = i & 15;
      const float* wp = &w[((size_t)(oc0 + oc_l) * CIN + ic0) * 16 + kq * 4];
      float4 wv = *(const float4*)wp;
      Wl[(kq * 4 + 0) * 68 + oc_l] = wv.x;
      Wl[(kq * 4 + 1) * 68 + oc_l] = wv.y;
      Wl[(kq * 4 + 2) * 68 + oc_l] = wv.z;
      Wl[(kq * 4 + 3) * 68 + oc_l] = wv.w;
    }
    // stage input patch: 4 ic x 34 rows x 20 cols (cols >=18 zero-padded)
    for (int i = tid; i < 4 * 680; i += 256) {
      int ic_l = i / 680, rem = i - ic_l * 680;
      int rr = rem / 20, cc = rem - rr * 20;
      int ih = ihb + rr, iw = iwb + cc;
      float v = 0.f;
      if (cc < 18 && (unsigned)ih < (unsigned)HIN && (unsigned)iw < (unsigned)HIN)
        v = xn[(size_t)(ic0 + ic_l) * (HIN * HIN) + ih * HIN + iw];
      Xl[i] = v;
    }
    __syncthreads();
#pragma unroll
    for (int ic_l = 0; ic_l < 4; ++ic_l) {
#pragma unroll
      for (int tap = 0; tap < 16; ++tap) {
        const int k = ic_l * 16 + tap;
        const int kh = tap >> 2, kw = tap & 3;
        float4 a0 = *(const float4*)&Wl[k * 68 + ty * 8];
        float4 a1 = *(const float4*)&Wl[k * 68 + ty * 8 + 4];
        const float* bp = &Xl[ic_l * 680 + (brow0 + kh) * 20 + bcol0 + kw];
        float bb[4] = {bp[0], bp[160], bp[320], bp[480]};  // rows +8q
        float av[8] = {a0.x, a0.y, a0.z, a0.w, a1.x, a1.y, a1.z, a1.w};
#pragma unroll
        for (int i2 = 0; i2 < 8; ++i2)
#pragma unroll
          for (int q = 0; q < 4; ++q)
            acc[i2][q] = fmaf(av[i2], bb[q], acc[i2][q]);
      }
    }
  }
  float* yn = y + ((size_t)n * COUT + oc0) * (HOUT * HOUT);
#pragma unroll
  for (int i = 0; i < 8; ++i) {
    float bbias = bl[ty * 8 + i];
#pragma unroll
    for (int q = 0; q < 4; ++q) {
      int u = (tx >> 3) + 4 * q, v = tx & 7;
      float vv = acc[i][q] + bbias;
      if (RELU) vv = fmaxf(vv, 0.f);
      yn[(size_t)(ty * 8 + i) * (HOUT * HOUT) + (oh0 + u) * HOUT + (ow0 + v)] = vv;
    }
  }
}

// ---------------------------------------------------------------------------
// cb_convert: cb fp32 -> bf16 hi/lo (vq A-side + decoder gather source).
// ---------------------------------------------------------------------------
__global__ __launch_bounds__(256) void cb_convert(
    const float* __restrict__ cb, short* __restrict__ cbh, short* __restrict__ cbl)
{
  const int g = blockIdx.x * 256 + threadIdx.x;
  const float* p = cb + (size_t)g * 8;
  short hs[8], ls[8];
#pragma unroll
  for (int u = 0; u < 8; ++u) {
    float v = p[u];
    short h = f2bf(v);
    hs[u] = h;
    ls[u] = f2bf(v - bf2f(h));
  }
  *(short8*)(cbh + (size_t)g * 8) = *(short8*)hs;
  *(short8*)(cbl + (size_t)g * 8) = *(short8*)ls;
}

// ---------------------------------------------------------------------------
// featT_prep2: feat[16][256][1024] fp32 -> featT fp32 [tok][256] (exact bits)
// + fth/ftl bf16 hi/lo pairs for the R3-proven vq approx.
// ---------------------------------------------------------------------------
__global__ __launch_bounds__(256) void featT_prep2(
    const float* __restrict__ feat, float* __restrict__ featT,
    short* __restrict__ fth, short* __restrict__ ftl)
{
  __shared__ float T[64][65];
  const int b = blockIdx.z, k0 = blockIdx.y * 64, t0 = blockIdx.x * 64;
  const float* fb = feat + ((size_t)b * 256 + k0) * 1024 + t0;
  const int tid = threadIdx.x;
#pragma unroll
  for (int r = 0; r < 16; ++r) {
    int idx = r * 256 + tid;
    int kk = idx >> 6, tt = idx & 63;
    T[tt][kk] = fb[(size_t)kk * 1024 + tt];
  }
  __syncthreads();
#pragma unroll
  for (int r = 0; r < 4; ++r) {
    int i = r * 256 + tid;            // 0..1023
    int tt = i >> 4, kq = i & 15;
    float v0 = T[tt][kq * 4 + 0], v1 = T[tt][kq * 4 + 1];
    float v2 = T[tt][kq * 4 + 2], v3 = T[tt][kq * 4 + 3];
    size_t off = ((size_t)(b * 1024 + t0 + tt)) * 256 + k0 + kq * 4;
    *(float4*)(featT + off) = make_float4(v0, v1, v2, v3);
    short4 hh, ll;
    hh.x = f2bf(v0); ll.x = f2bf(v0 - bf2f(hh.x));
    hh.y = f2bf(v1); ll.y = f2bf(v1 - bf2f(hh.y));
    hh.z = f2bf(v2); ll.z = f2bf(v2 - bf2f(hh.z));
    hh.w = f2bf(v3); ll.w = f2bf(v3 - bf2f(hh.w));
    *(short4*)(fth + off) = hh;
    *(short4*)(ftl + off) = ll;
  }
}

// ---------------------------------------------------------------------------
// vq_mfma: R3-proven verbatim — bf16 hi/lo x3 MFMA, per-block top-2 per token.
// ---------------------------------------------------------------------------
__global__ __launch_bounds__(256) void vq_mfma(
    const short* __restrict__ cbh, const short* __restrict__ cbl,
    const short* __restrict__ fth, const short* __restrict__ ftl,
    float2* __restrict__ pval, int2* __restrict__ pidx)
{
  __shared__ __align__(16) short Ah[4 * 128 * 8];
  __shared__ __align__(16) short Al2[4 * 128 * 8];
  __shared__ __align__(16) short Bh[4 * 128 * 8];
  __shared__ __align__(16) short Bl2[4 * 128 * 8];
  const int tid = threadIdx.x;
  const int w = tid >> 6, lane = tid & 63;
  const int wm = w >> 1, wn = w & 1;
  const int tg = blockIdx.x, cg = blockIdx.y;
  const int code0 = cg * 128, tok0 = tg * 128;
  const int kgl = lane >> 4, cl = lane & 15;

  f32x4 acc[4][4];
#pragma unroll
  for (int i = 0; i < 4; ++i)
#pragma unroll
    for (int j = 0; j < 4; ++j) acc[i][j] = (f32x4){0.f, 0.f, 0.f, 0.f};

  const int i0 = w * 128;
  for (int kc = 0; kc < 256; kc += 32) {
    __syncthreads();
#pragma unroll
    for (int rep = 0; rep < 2; ++rep) {
      int ib = i0 + rep * 64;
      int i = ib + lane;
      int m = i & 127, kg = i >> 7;
      size_t goffA = (size_t)(code0 + m) * 256 + kc + kg * 8;
      size_t goffB = (size_t)(tok0 + m) * 256 + kc + kg * 8;
      int loff = ib * 8;
      ld16(cbh + goffA, Ah + loff);
      ld16(cbl + goffA, Al2 + loff);
      ld16(fth + goffB, Bh + loff);
      ld16(ftl + goffB, Bl2 + loff);
    }
    __syncthreads();
    short8 ah[4], al[4], bh[4], bl[4];
#pragma unroll
    for (int mt = 0; mt < 4; ++mt) {
      int row = wm * 64 + mt * 16 + cl;
      ah[mt] = *(const short8*)&Ah[(kgl * 128 + row) * 8];
      al[mt] = *(const short8*)&Al2[(kgl * 128 + row) * 8];
    }
#pragma unroll
    for (int nt = 0; nt < 4; ++nt) {
      int row = wn * 64 + nt * 16 + cl;
      bh[nt] = *(const short8*)&Bh[(kgl * 128 + row) * 8];
      bl[nt] = *(const short8*)&Bl2[(kgl * 128 + row) * 8];
    }
#pragma unroll
    for (int mt = 0; mt < 4; ++mt)
#pragma unroll
      for (int nt = 0; nt < 4; ++nt) {
        acc[mt][nt] = __builtin_amdgcn_mfma_f32_16x16x32_bf16(
            ah[mt], bh[nt], acc[mt][nt], 0, 0, 0);
        acc[mt][nt] = __builtin_amdgcn_mfma_f32_16x16x32_bf16(
            ah[mt], bl[nt], acc[mt][nt], 0, 0, 0);
        acc[mt][nt] = __builtin_amdgcn_mfma_f32_16x16x32_bf16(
            al[mt], bh[nt], acc[mt][nt], 0, 0, 0);
      }
  }
  __syncthreads();

  float* Sv = (float*)Ah;
  int* Si = (int*)Bh;
#pragma unroll
  for (int nt = 0; nt < 4; ++nt) {
    float v1 = -3.4e38f, v2 = -3.4e38f;
    int j1 = 0, j2 = 0;
#pragma unroll
    for (int mt = 0; mt < 4; ++mt) {
      int cb2 = code0 + wm * 64 + mt * 16 + kgl * 4;
      f32x4 a = acc[mt][nt];
#pragma unroll
      for (int r = 0; r < 4; ++r) {
        float val = a[r];
        int code = cb2 + r;
        if (val > v1) { v2 = v1; j2 = j1; v1 = val; j1 = code; }
        else if (val > v2) { v2 = val; j2 = code; }
      }
    }
    for (int mk = 16; mk < 64; mk <<= 1) {
      float ov1 = __shfl_xor(v1, mk);
      int oj1 = __shfl_xor(j1, mk);
      float ov2 = __shfl_xor(v2, mk);
      int oj2 = __shfl_xor(j2, mk);
      if (ov1 > v1) {
        if (v1 >= ov2) { v2 = v1; j2 = j1; } else { v2 = ov2; j2 = oj2; }
        v1 = ov1; j1 = oj1;
      } else if (ov1 > v2) { v2 = ov1; j2 = oj1; }
    }
    if (lane < 16) {
      int tl = wn * 64 + nt * 16 + lane;
      Sv[(wm * 128 + tl) * 2 + 0] = v1;
      Sv[(wm * 128 + tl) * 2 + 1] = v2;
      Si[(wm * 128 + tl) * 2 + 0] = j1;
      Si[(wm * 128 + tl) * 2 + 1] = j2;
    }
  }
  __syncthreads();
  if (tid < 128) {
    int tl = tid;
    float v1 = Sv[tl * 2], v2 = Sv[tl * 2 + 1];
    int j1 = Si[tl * 2], j2 = Si[tl * 2 + 1];
    float ov1 = Sv[(128 + tl) * 2], ov2 = Sv[(128 + tl) * 2 + 1];
    int oj1 = Si[(128 + tl) * 2], oj2 = Si[(128 + tl) * 2 + 1];
    if (ov1 > v1) {
      if (v1 >= ov2) { v2 = v1; j2 = j1; } else { v2 = ov2; j2 = oj2; }
      v1 = ov1; j1 = oj1;
    } else if (ov1 > v2) { v2 = ov1; j2 = oj1; }
    size_t o = (size_t)cg * 16384 + tok0 + tl;
    pval[o] = make_float2(v1, v2);
    pidx[o] = make_int2(j1, j2);
  }
}

// ---------------------------------------------------------------------------
// vq_rescore: merge 64 block-partials -> top-4 -> exact fp32 dots vs
// featT[tok][256] (same fmaf order as R3 -> identical bits/indices).
// ---------------------------------------------------------------------------
__global__ __launch_bounds__(256) void vq_rescore(
    const float2* __restrict__ pval, const int2* __restrict__ pidx,
    const float* __restrict__ featT, const float* __restrict__ cb,
    int* __restrict__ fidx, float* __restrict__ idx_out)
{
  const int t = blockIdx.x * 256 + threadIdx.x;
  float vs[4] = {-3.4e38f, -3.4e38f, -3.4e38f, -3.4e38f};
  int is[4] = {0, 0, 0, 0};
  for (int cgi = 0; cgi < 64; ++cgi) {
    float2 pv = pval[(size_t)cgi * 16384 + t];
    int2 pi = pidx[(size_t)cgi * 16384 + t];
#pragma unroll
    for (int s = 0; s < 2; ++s) {
      float v = s ? pv.y : pv.x;
      int ii = s ? pi.y : pi.x;
      if (v > vs[3]) {
        vs[3] = v; is[3] = ii;
#pragma unroll
        for (int k = 3; k > 0; --k)
          if (vs[k] > vs[k - 1]) {
            float tv = vs[k]; vs[k] = vs[k - 1]; vs[k - 1] = tv;
            int ti = is[k]; is[k] = is[k - 1]; is[k - 1] = ti;
          }
      }
    }
  }
  const float4* fc = (const float4*)(featT + (size_t)t * 256);
  const float4* c0 = (const float4*)(cb + (size_t)is[0] * 256);
  const float4* c1 = (const float4*)(cb + (size_t)is[1] * 256);
  const float4* c2 = (const float4*)(cb + (size_t)is[2] * 256);
  const float4* c3 = (const float4*)(cb + (size_t)is[3] * 256);
  float s0 = 0.f, s1 = 0.f, s2 = 0.f, s3 = 0.f;
  for (int k4 = 0; k4 < 64; ++k4) {
    float4 f = fc[k4];
    float4 w0 = c0[k4], w1 = c1[k4], w2 = c2[k4], w3 = c3[k4];
    s0 = fmaf(w0.x, f.x, fmaf(w0.y, f.y, fmaf(w0.z, f.z, fmaf(w0.w, f.w, s0))));
    s1 = fmaf(w1.x, f.x, fmaf(w1.y, f.y, fmaf(w1.z, f.z, fmaf(w1.w, f.w, s1))));
    s2 = fmaf(w2.x, f.x, fmaf(w2.y, f.y, fmaf(w2.z, f.z, fmaf(w2.w, f.w, s2))));
    s3 = fmaf(w3.x, f.x, fmaf(w3.y, f.y, fmaf(w3.z, f.z, fmaf(w3.w, f.w, s3))));
  }
  float best = s0; int bi = is[0];
  float sv[3] = {s1, s2, s3};
  int si2[3] = {is[1], is[2], is[3]};
#pragma unroll
  for (int c = 0; c < 3; ++c)
    if (sv[c] > best || (sv[c] == best && si2[c] < bi)) { best = sv[c]; bi = si2[c]; }
  fidx[t] = bi;
  idx_out[t] = (float)bi;
}

// ---------------------------------------------------------------------------
// wpack / gather2 / deconv_mfma / deconv3  (decoder — verbatim, proven)
// ---------------------------------------------------------------------------
template <int COUT, int CIN>
__global__ __launch_bounds__(256) void wpack(
    const float* __restrict__ w, short* __restrict__ Ah, short* __restrict__ Al)
{
  constexpr int K = 4 * CIN;
  const int idx = blockIdx.x * 256 + threadIdx.x;
  const int par = idx / (COUT * K);
  const int rem = idx % (COUT * K);
  const int oc = rem / K;
  const int k = rem % K;
  const int kk = k / CIN, ic = k % CIN;
  const int kh = 2 * (kk >> 1) + (par >> 1);
  const int kw = 2 * (kk & 1) + (par & 1);
  float v = w[(((size_t)oc * CIN + ic) * 4 + kh) * 4 + kw];
  short h = f2bf(v);
  Ah[idx] = h;
  Al[idx] = f2bf(v - bf2f(h));
}

__global__ __launch_bounds__(256) void gather2(
    const short* __restrict__ cbh, const short* __restrict__ cbl,
    const int* __restrict__ fidx, short* __restrict__ qTh, short* __restrict__ qTl)
{
  const int tid = threadIdx.x;
  const int gt = blockIdx.x * 64 + (tid >> 2);
  const int part = tid & 3;
  const int code = fidx[gt];
  const short8* sh = (const short8*)(cbh + (size_t)code * 256 + part * 64);
  const short8* sl = (const short8*)(cbl + (size_t)code * 256 + part * 64);
  short8* dh = (short8*)(qTh + (size_t)gt * 256 + part * 64);
  short8* dl = (short8*)(qTl + (size_t)gt * 256 + part * 64);
#pragma unroll
  for (int j = 0; j < 8; ++j) { dh[j] = sh[j]; dl[j] = sl[j]; }
}

template <int CIN, int GRID, int COUT, int NPX, int WM, int WN, bool OUT_HALF>
__global__ __launch_bounds__(256) void deconv_mfma(
    const short* __restrict__ inh, const short* __restrict__ inl,
    const short* __restrict__ Aph, const short* __restrict__ Apl,
    const float* __restrict__ bias, void* __restrict__ out_h,
    void* __restrict__ out_l, const short* __restrict__ zp)
{
  constexpr int K = 4 * CIN, HOUT = 2 * GRID, AE = 4 * COUT, BE = 4 * NPX;
  constexpr int GS = (GRID == 32) ? 5 : 6;
  __shared__ __align__(16) short AhL[AE * 8];
  __shared__ __align__(16) short AlL[AE * 8];
  __shared__ __align__(16) short BhL[BE * 8];
  __shared__ __align__(16) short BlL[BE * 8];
  __shared__ float bl[COUT];
  const int tid = threadIdx.x;
  const int w = tid >> 6, lane = tid & 63;
  const int wm = w / WN, wn = w % WN;
  const int kgl = lane >> 4, cl = lane & 15;
  const int par = blockIdx.y, n = blockIdx.z;
  const int pr = par >> 1, pc = par & 1;
  const int Ut0 = blockIdx.x * (NPX / GRID);
  if (tid < COUT) bl[tid] = bias[tid];

  f32x4 acc[4][4];
#pragma unroll
  for (int i = 0; i < 4; ++i)
#pragma unroll
    for (int j = 0; j < 4; ++j) acc[i][j] = (f32x4){0.f, 0.f, 0.f, 0.f};

  for (int kc = 0; kc < K; kc += 32) {
    const int kk = kc / CIN, ic0 = kc % CIN;
    const int dr = (kk >> 1) + pr - 1, dc = (kk & 1) + pc - 1;
    __syncthreads();
#pragma unroll
    for (int rep = 0; rep < AE / 256; ++rep) {
      int e = rep * 256 + tid;
      int kg = e / COUT, oc_l = e % COUT;
      size_t go = ((size_t)(par * COUT + oc_l)) * K + kc + kg * 8;
      int lo = (e & ~63) * 8;
      ld16(Aph + go, AhL + lo);
      ld16(Apl + go, AlL + lo);
    }
#pragma unroll
    for (int rep = 0; rep < BE / 256; ++rep) {
      int e = rep * 256 + tid;
      int kg = e / NPX, m = e % NPX;
      int sU = Ut0 + (m >> GS) + dr;
      int sV = (m & (GRID - 1)) + dc;
      bool ok = (unsigned)sU < (unsigned)GRID && (unsigned)sV < (unsigned)GRID;
      long pix = (long)(n * GRID + sU) * GRID + sV;
      size_t go = (size_t)(pix * CIN + ic0 + kg * 8);
      int lo = (e & ~63) * 8;
      ld16(ok ? inh + go : zp, BhL + lo);
      ld16(ok ? inl + go : zp, BlL + lo);
    }
    __syncthreads();
    short8 ah[4], al[4], bh[4], blo[4];
#pragma unroll
    for (int mt = 0; mt < 4; ++mt) {
      int row = kgl * COUT + wm * 64 + mt * 16 + cl;
      ah[mt] = *(const short8*)&AhL[row * 8];
      al[mt] = *(const short8*)&AlL[row * 8];
    }
#pragma unroll
    for (int nt = 0; nt < 4; ++nt) {
      int row = kgl * NPX + wn * 64 + nt * 16 + cl;
      bh[nt] = *(const short8*)&BhL[row * 8];
      blo[nt] = *(const short8*)&BlL[row * 8];
    }
#pragma unroll
    for (int mt = 0; mt < 4; ++mt)
#pragma unroll
      for (int nt = 0; nt < 4; ++nt) {
        acc[mt][nt] = __builtin_amdgcn_mfma_f32_16x16x32_bf16(
            ah[mt], bh[nt], acc[mt][nt], 0, 0, 0);
        acc[mt][nt] = __builtin_amdgcn_mfma_f32_16x16x32_bf16(
            ah[mt], blo[nt], acc[mt][nt], 0, 0, 0);
        acc[mt][nt] = __builtin_amdgcn_mfma_f32_16x16x32_bf16(
            al[mt], bh[nt], acc[mt][nt], 0, 0, 0);
      }
  }
#pragma unroll
  for (int mt = 0; mt < 4; ++mt) {
    const int oc = wm * 64 + mt * 16 + kgl * 4;
    const float4 bv = *(const float4*)&bl[oc];
#pragma unroll
    for (int nt = 0; nt < 4; ++nt) {
      const int px = wn * 64 + nt * 16 + cl;
      const int U = Ut0 + (px >> GS), V = px & (GRID - 1);
      const int r = 2 * U + pr, c = 2 * V + pc;
      const size_t ob = ((size_t)n * HOUT * HOUT + (size_t)r * HOUT + c) * COUT + oc;
      float v0 = fmaxf(acc[mt][nt][0] + bv.x, 0.f);
      float v1 = fmaxf(acc[mt][nt][1] + bv.y, 0.f);
      float v2 = fmaxf(acc[mt][nt][2] + bv.z, 0.f);
      float v3 = fmaxf(acc[mt][nt][3] + bv.w, 0.f);
      if constexpr (OUT_HALF) {
        ushort4 s;
        s.x = __half_as_ushort(__float2half(v0));
        s.y = __half_as_ushort(__float2half(v1));
        s.z = __half_as_ushort(__float2half(v2));
        s.w = __half_as_ushort(__float2half(v3));
        *(ushort4*)((unsigned short*)out_h + ob) = s;
      } else {
        short4 hh, ll;
        hh.x = f2bf(v0); ll.x = f2bf(v0 - bf2f(hh.x));
        hh.y = f2bf(v1); ll.y = f2bf(v1 - bf2f(hh.y));
        hh.z = f2bf(v2); ll.z = f2bf(v2 - bf2f(hh.z));
        hh.w = f2bf(v3); ll.w = f2bf(v3 - bf2f(hh.w));
        *(short4*)((short*)out_h + ob) = hh;
        *(short4*)((short*)out_l + ob) = ll;
      }
    }
  }
}

__global__ __launch_bounds__(256) void deconv3_kernel(
    const __half* __restrict__ d2, const float* __restrict__ w,
    const float* __restrict__ bias, float* __restrict__ y)
{
  __shared__ __align__(16) float Xl[108 * 68];
  __shared__ __align__(16) float wl[4 * 4 * 3 * 64];
  const int tid = threadIdx.x;
  for (int i = tid; i < 3072; i += 256) {
    int oc = i >> 10, ic = (i >> 4) & 63, kh = (i >> 2) & 3, kw = i & 3;
    int par = (kh & 1) * 2 + (kw & 1), kidx = (kh >> 1) * 2 + (kw >> 1);
    wl[((par * 4 + kidx) * 3 + oc) * 64 + ic] = w[i];
  }
  const int n = blockIdx.z, r0 = blockIdx.y * 8, c0 = blockIdx.x * 32;
  const int gr0 = (r0 >> 1) - 1, gc0 = (c0 >> 1) - 1;
  for (int e = tid; e < 1728; e += 256) {
    int pl = e >> 4, sub = e & 15;
    int rr = pl / 18, cc = pl - rr * 18;
    int gr = gr0 + rr, gc = gc0 + cc;
    float4 v = make_float4(0.f, 0.f, 0.f, 0.f);
    if ((unsigned)gr < 128u && (unsigned)gc < 128u) {
      const __half2* p =
          (const __half2*)(d2 + ((size_t)(n * 16384 + gr * 128 + gc) * 64 + sub * 4));
      float2 f0 = __half22float2(p[0]);
      float2 f1 = __half22float2(p[1]);
      v = make_float4(f0.x, f0.y, f1.x, f1.y);
    }
    *(float4*)&Xl[pl * 68 + sub * 4] = v;
  }
  __syncthreads();
  const int wv = tid >> 6, lane = tid & 63;
  const int pr = wv >> 1, pc = wv & 1;
  const int Ul = lane >> 4, Vl = lane & 15;
  float a0 = bias[0], a1 = bias[1], a2 = bias[2];
  const int parb = wv * 768;
#pragma unroll
  for (int ic4 = 0; ic4 < 16; ++ic4) {
    float4 xv[4];
#pragma unroll
    for (int t = 0; t < 4; ++t) {
      int lr = Ul + (t >> 1) + pr, lc = Vl + (t & 1) + pc;
      xv[t] = *(const float4*)&Xl[(lr * 18 + lc) * 68 + ic4 * 4];
    }
#pragma unroll
    for (int t = 0; t < 4; ++t) {
      float4 w0 = *(const float4*)&wl[parb + (t * 3 + 0) * 64 + ic4 * 4];
      float4 w1 = *(const float4*)&wl[parb + (t * 3 + 1) * 64 + ic4 * 4];
      float4 w2 = *(const float4*)&wl[parb + (t * 3 + 2) * 64 + ic4 * 4];
      a0 = fmaf(w0.x, xv[t].x, fmaf(w0.y, xv[t].y, fmaf(w0.z, xv[t].z, fmaf(w0.w, xv[t].w, a0))));
      a1 = fmaf(w1.x, xv[t].x, fmaf(w1.y, xv[t].y, fmaf(w1.z, xv[t].z, fmaf(w1.w, xv[t].w, a1))));
      a2 = fmaf(w2.x, xv[t].x, fmaf(w2.y, xv[t].y, fmaf(w2.z, xv[t].z, fmaf(w2.w, xv[t].w, a2))));
    }
  }
  const int r = r0 + 2 * Ul + pr, c = c0 + 2 * Vl + pc;
  float* yn = y + (size_t)n * 3 * 65536 + r * 256 + c;
  yn[0] = a0;
  yn[65536] = a1;
  yn[131072] = a2;
}

// ---------------------------------------------------------------------------
extern "C" void kernel_launch(void* const* d_in, const int* in_sizes, int n_in,
                              void* d_out, int out_size, void* d_ws, size_t ws_size,
                              hipStream_t stream)
{
  const float* x   = (const float*)d_in[0];
  const float* ew1 = (const float*)d_in[1];
  const float* eb1 = (const float*)d_in[2];
  const float* ew2 = (const float*)d_in[3];
  const float* eb2 = (const float*)d_in[4];
  const float* ew3 = (const float*)d_in[5];
  const float* eb3 = (const float*)d_in[6];
  const float* cb  = (const float*)d_in[7];
  const float* dw1 = (const float*)d_in[8];
  const float* db1 = (const float*)d_in[9];
  const float* dw2 = (const float*)d_in[10];
  const float* db2 = (const float*)d_in[11];
  const float* dw3 = (const float*)d_in[12];
  const float* db3 = (const float*)d_in[13];

  float* recon = (float*)d_out;
  float* idxf  = (float*)d_out + 3145728;
  unsigned short* zp = (unsigned short*)d_out;   // [0,4K) zero page

  char* ws = (char*)d_ws;
  // Workspace map (96 MiB, liveness-aliased; all offsets audited):
  float* h1   = (float*)ws;                         // [0,64M)   conv1 out fp32
  float* h2   = (float*)(ws + 67108864);            // [64M,96M) conv2 out fp32
  float* feat = (float*)ws;                         // [0,16M)   conv3 out (h1 dead)
  short* cbh  = (short*)(ws + 16777216);            // [16M,20M) (after conv2)
  short* cbl  = (short*)(ws + 20971520);            // [20M,24M)
  float* featT = (float*)(ws + 25165824);           // [24M,40M) fp32 [tok][256]
  short* fth  = (short*)(ws + 41943040);            // [40M,48M)
  short* ftl  = (short*)(ws + 50331648);            // [48M,56M)
  float2* pval = (float2*)(ws + 67108864);          // [64M,72M) (h2 dead)
  int2*   pidx = (int2*)(ws + 75497472);            // [72M,80M)
  int*    fidx = (int*)(ws + 83886080);             // [80M,+64K)
  short* A1h = (short*)(ws + 92274688);             // [88M,89M)
  short* A1l = (short*)(ws + 93323264);             // [89M,90M)
  short* A2h = (short*)(ws + 94371840);             // [90M,+256K)
  short* A2l = (short*)(ws + 94633984);             // [+256K)
  short* qTh = (short*)ws;                          // [0,8M)   (feat dead)
  short* qTl = (short*)(ws + 8388608);              // [8M,16M)
  short* d1h = (short*)(ws + 25165824);             // [24M,40M) (featT dead)
  short* d1l = (short*)(ws + 41943040);             // [40M,56M) (fth/ftl dead)
  __half* d2 = (__half*)(ws + 58720256);            // [56M,88M) (pval/pidx/fidx dead)

  zfill<<<dim3(1), 256, 0, stream>>>((float4*)zp);

  conv1_kernel<<<dim3(64, 16), 256, 0, stream>>>(x, ew1, eb1, h1);
  conv_s2<64, 128, 128, true><<<dim3(32, 2, 16), 256, 0, stream>>>(h1, ew2, eb2, h2);
  cb_convert<<<dim3(1024), 256, 0, stream>>>(cb, cbh, cbl);
  conv_s2<128, 64, 256, false><<<dim3(8, 4, 16), 256, 0, stream>>>(h2, ew3, eb3, feat);

  featT_prep2<<<dim3(16, 4, 16), 256, 0, stream>>>(feat, featT, fth, ftl);
  vq_mfma<<<dim3(128, 64), 256, 0, stream>>>(cbh, cbl, fth, ftl, pval, pidx);
  vq_rescore<<<dim3(64), 256, 0, stream>>>(pval, pidx, featT, cb, fidx, idxf);

  wpack<128, 256><<<dim3(2048), 256, 0, stream>>>(dw1, A1h, A1l);
  wpack<64, 128><<<dim3(512), 256, 0, stream>>>(dw2, A2h, A2l);
  gather2<<<dim3(256), 256, 0, stream>>>(cbh, cbl, fidx, qTh, qTl);

  deconv_mfma<256, 32, 128, 128, 2, 2, false>
      <<<dim3(8, 4, 16), 256, 0, stream>>>(qTh, qTl, A1h, A1l, db1, d1h, d1l,
                                           (const short*)zp);
  deconv_mfma<128, 64, 64, 256, 1, 4, true>
      <<<dim3(16, 4, 16), 256, 0, stream>>>(d1h, d1l, A2h, A2l, db2, d2, d2,
                                            (const short*)zp);
  deconv3_kernel<<<dim3(8, 32, 16), 256, 0, stream>>>(d2, dw3, db3, recon);
}